// Round 1
// baseline (2952.269 us; speedup 1.0000x reference)
//
#include <hip/hip_runtime.h>
#include <math.h>

// ---------------- e1: conv 1->32, k4 s2 p1, (64,1,256,256) -> (64,32,128,128), relu
__global__ __launch_bounds__(256) void k_e1(const float* __restrict__ x,
                                            const float* __restrict__ w,   // (32,1,4,4)
                                            const float* __restrict__ b,
                                            float* __restrict__ out) {
    int idx = blockIdx.x * 256 + threadIdx.x;        // 64*128*128
    int ow = idx & 127, oh = (idx >> 7) & 127, n = idx >> 14;
    const float* xn = x + (size_t)n * 65536;
    float patch[16];
#pragma unroll
    for (int kh = 0; kh < 4; kh++) {
        int ih = 2 * oh + kh - 1;
#pragma unroll
        for (int kw = 0; kw < 4; kw++) {
            int iw = 2 * ow + kw - 1;
            bool ok = ((unsigned)ih < 256u) & ((unsigned)iw < 256u);
            patch[kh * 4 + kw] = ok ? xn[ih * 256 + iw] : 0.f;
        }
    }
    float* on = out + (size_t)n * 524288 + oh * 128 + ow;
#pragma unroll
    for (int oc = 0; oc < 32; oc++) {
        float acc = b[oc];
#pragma unroll
        for (int t = 0; t < 16; t++) acc += patch[t] * w[oc * 16 + t];
        on[oc * 16384] = fmaxf(acc, 0.f);
    }
}

// ---------------- e2: conv 32->64, k4 s2 p1, (64,32,128,128) -> (64,64,64,64), relu
__global__ __launch_bounds__(256) void k_e2(const float* __restrict__ x,
                                            const float* __restrict__ w,   // (64,32,4,4)
                                            const float* __restrict__ b,
                                            float* __restrict__ out) {
    int idx = blockIdx.x * 256 + threadIdx.x;        // 64*64*64
    int ow = idx & 63, oh = (idx >> 6) & 63, n = idx >> 12;
    float acc[64];
#pragma unroll
    for (int oc = 0; oc < 64; oc++) acc[oc] = b[oc];
    const float* xn = x + (size_t)n * 524288;
    for (int ic = 0; ic < 32; ic++) {
        float patch[16];
        const float* xc = xn + ic * 16384;
#pragma unroll
        for (int kh = 0; kh < 4; kh++) {
            int ih = 2 * oh + kh - 1;
#pragma unroll
            for (int kw = 0; kw < 4; kw++) {
                int iw = 2 * ow + kw - 1;
                bool ok = ((unsigned)ih < 128u) & ((unsigned)iw < 128u);
                patch[kh * 4 + kw] = ok ? xc[ih * 128 + iw] : 0.f;
            }
        }
        const float* wc = w + ic * 16;               // w[oc*512 + ic*16 + t]
#pragma unroll
        for (int oc = 0; oc < 64; oc++) {
#pragma unroll
            for (int t = 0; t < 16; t++) acc[oc] += patch[t] * wc[oc * 512 + t];
        }
    }
    float* on = out + (size_t)n * 262144 + oh * 64 + ow;
#pragma unroll
    for (int oc = 0; oc < 64; oc++) on[oc * 4096] = fmaxf(acc[oc], 0.f);
}

// ---------------- e3: conv 64->64, k3 s1 p1, (64,64,64,64) -> (64,64,64,64), relu
__global__ __launch_bounds__(256) void k_e3(const float* __restrict__ x,
                                            const float* __restrict__ w,   // (64,64,3,3)
                                            const float* __restrict__ b,
                                            float* __restrict__ out) {
    int idx = blockIdx.x * 256 + threadIdx.x;        // 64*64*64
    int ow = idx & 63, oh = (idx >> 6) & 63, n = idx >> 12;
    float acc[64];
#pragma unroll
    for (int oc = 0; oc < 64; oc++) acc[oc] = b[oc];
    const float* xn = x + (size_t)n * 262144;
    for (int ic = 0; ic < 64; ic++) {
        float patch[9];
        const float* xc = xn + ic * 4096;
#pragma unroll
        for (int kh = 0; kh < 3; kh++) {
            int ih = oh + kh - 1;
#pragma unroll
            for (int kw = 0; kw < 3; kw++) {
                int iw = ow + kw - 1;
                bool ok = ((unsigned)ih < 64u) & ((unsigned)iw < 64u);
                patch[kh * 3 + kw] = ok ? xc[ih * 64 + iw] : 0.f;
            }
        }
        const float* wc = w + ic * 9;                // w[oc*576 + ic*9 + t]
#pragma unroll
        for (int oc = 0; oc < 64; oc++) {
#pragma unroll
            for (int t = 0; t < 9; t++) acc[oc] += patch[t] * wc[oc * 576 + t];
        }
    }
    float* on = out + (size_t)n * 262144 + oh * 64 + ow;
#pragma unroll
    for (int oc = 0; oc < 64; oc++) on[oc * 4096] = fmaxf(acc[oc], 0.f);
}

// ---------------- codebook half-norms: hn[j] = 0.5*||emb_j||^2
__global__ __launch_bounds__(256) void k_hn(const float* __restrict__ emb,
                                            float* __restrict__ hn) {
    int j = blockIdx.x * 256 + threadIdx.x;
    if (j < 512) {
        float s = 0.f;
#pragma unroll
        for (int c = 0; c < 64; c++) { float v = emb[j * 64 + c]; s += v * v; }
        hn[j] = 0.5f * s;
    }
}

// ---------------- VQ: argmax_j (z.e_j - 0.5||e_j||^2)  ==  argmin_j dist, zq = emb[best]
__global__ __launch_bounds__(256) void k_vq(const float* __restrict__ ze,
                                            const float* __restrict__ emb,  // (512,64)
                                            const float* __restrict__ hn,
                                            float* __restrict__ zq) {
    int idx = blockIdx.x * 256 + threadIdx.x;        // 64*4096 locations
    int hw = idx & 4095, n = idx >> 12;
    const float* zp = ze + (size_t)n * 262144 + hw;
    float z[64];
#pragma unroll
    for (int c = 0; c < 64; c++) z[c] = zp[c * 4096];
    float best = -3.4e38f;
    int bj = 0;
    for (int j = 0; j < 512; j++) {
        const float* ej = emb + j * 64;
        float s = -hn[j];
#pragma unroll
        for (int c = 0; c < 64; c++) s += z[c] * ej[c];
        if (s > best) { best = s; bj = j; }          // strict > keeps first index (matches argmin tie-break)
    }
    const float* eb = emb + bj * 64;
    float* qp = zq + (size_t)n * 262144 + hw;
#pragma unroll
    for (int c = 0; c < 64; c++) qp[c * 4096] = eb[c];
}

// ---------------- d1: conv-transpose as conv: 64->32, k3 s1 p1 (w flipped), relu
__global__ __launch_bounds__(256) void k_d1(const float* __restrict__ x,   // zq (64,64,64,64)
                                            const float* __restrict__ w,   // (64,32,3,3) [in][out][kh][kw]
                                            const float* __restrict__ b,
                                            float* __restrict__ out) {    // (64,32,64,64)
    int idx = blockIdx.x * 256 + threadIdx.x;        // 64*64*64
    int ow = idx & 63, oh = (idx >> 6) & 63, n = idx >> 12;
    float acc[32];
#pragma unroll
    for (int oc = 0; oc < 32; oc++) acc[oc] = b[oc];
    const float* xn = x + (size_t)n * 262144;
    for (int ic = 0; ic < 64; ic++) {
        float patch[9];
        const float* xc = xn + ic * 4096;
#pragma unroll
        for (int kh = 0; kh < 3; kh++) {
            int ih = oh + kh - 1;
#pragma unroll
            for (int kw = 0; kw < 3; kw++) {
                int iw = ow + kw - 1;
                bool ok = ((unsigned)ih < 64u) & ((unsigned)iw < 64u);
                patch[kh * 3 + kw] = ok ? xc[ih * 64 + iw] : 0.f;
            }
        }
        const float* wc = w + ic * 288;              // + oc*9 + (2-kh)*3 + (2-kw)
#pragma unroll
        for (int oc = 0; oc < 32; oc++) {
#pragma unroll
            for (int kh = 0; kh < 3; kh++)
#pragma unroll
                for (int kw = 0; kw < 3; kw++)
                    acc[oc] += patch[kh * 3 + kw] * wc[oc * 9 + (2 - kh) * 3 + (2 - kw)];
        }
    }
    float* on = out + (size_t)n * 131072 + oh * 64 + ow;
#pragma unroll
    for (int oc = 0; oc < 32; oc++) on[oc * 4096] = fmaxf(acc[oc], 0.f);
}

// ---------------- d2: conv-transpose 32->64, k4 s2 p1, (64,32,64,64) -> (64,64,128,128), relu
// gather form: per output parity, 2x2 live taps. Parity carried in blockIdx bits => uniform weight idx.
__global__ __launch_bounds__(256) void k_d2(const float* __restrict__ x,
                                            const float* __restrict__ w,   // (32,64,4,4) [in][out][kh][kw]
                                            const float* __restrict__ b,
                                            float* __restrict__ out) {
    int bi = blockIdx.x;                             // 64n * 2ph * 2pw * 16ohhi = 4096
    int ohhi = bi & 15;
    int pw = (bi >> 4) & 1;
    int ph = (bi >> 5) & 1;
    int n  = bi >> 6;
    int ow2 = threadIdx.x & 63;
    int oh2 = ohhi * 4 + (threadIdx.x >> 6);
    int oh = 2 * oh2 + ph, ow = 2 * ow2 + pw;
    int iha = oh2 + ph - 1, ihb = iha + 1;
    int iwa = ow2 + pw - 1, iwb = iwa + 1;
    bool va = iha >= 0, vb = ihb < 64;
    bool ua = iwa >= 0, ub = iwb < 64;
    // wt[oc][ic][kh][kw] = w[ic][oc][3-kh][3-kw]; kh in {ph, ph+2}, kw in {pw, pw+2}
    int i00 = (3 - ph) * 4 + (3 - pw), i01 = (3 - ph) * 4 + (1 - pw);
    int i10 = (1 - ph) * 4 + (3 - pw), i11 = (1 - ph) * 4 + (1 - pw);
    float acc[64];
#pragma unroll
    for (int oc = 0; oc < 64; oc++) acc[oc] = b[oc];
    const float* xn = x + (size_t)n * 131072;
    for (int ic = 0; ic < 32; ic++) {
        const float* xc = xn + ic * 4096;
        float p00 = (va & ua) ? xc[iha * 64 + iwa] : 0.f;
        float p01 = (va & ub) ? xc[iha * 64 + iwb] : 0.f;
        float p10 = (vb & ua) ? xc[ihb * 64 + iwa] : 0.f;
        float p11 = (vb & ub) ? xc[ihb * 64 + iwb] : 0.f;
        const float* wc = w + ic * 1024;
#pragma unroll
        for (int oc = 0; oc < 64; oc++) {
            const float* wo = wc + oc * 16;
            acc[oc] += p00 * wo[i00] + p01 * wo[i01] + p10 * wo[i10] + p11 * wo[i11];
        }
    }
    float* on = out + (size_t)n * 1048576 + oh * 128 + ow;
#pragma unroll
    for (int oc = 0; oc < 64; oc++) on[oc * 16384] = fmaxf(acc[oc], 0.f);
}

// ---------------- d3: conv-transpose 64->1, k4 s2 p1, (64,64,128,128) -> (64,1,256,256), no relu
__global__ __launch_bounds__(256) void k_d3(const float* __restrict__ x,
                                            const float* __restrict__ w,   // (64,1,4,4)
                                            const float* __restrict__ b,
                                            float* __restrict__ out) {
    int bi = blockIdx.x;                             // 64n * 2ph * 2pw * 64ohhi = 16384
    int ohhi = bi & 63;
    int pw = (bi >> 6) & 1;
    int ph = (bi >> 7) & 1;
    int n  = bi >> 8;
    int ow2 = threadIdx.x & 127;
    int oh2 = ohhi * 2 + (threadIdx.x >> 7);
    int oh = 2 * oh2 + ph, ow = 2 * ow2 + pw;
    int iha = oh2 + ph - 1, ihb = iha + 1;
    int iwa = ow2 + pw - 1, iwb = iwa + 1;
    bool va = iha >= 0, vb = ihb < 128;
    bool ua = iwa >= 0, ub = iwb < 128;
    int i00 = (3 - ph) * 4 + (3 - pw), i01 = (3 - ph) * 4 + (1 - pw);
    int i10 = (1 - ph) * 4 + (3 - pw), i11 = (1 - ph) * 4 + (1 - pw);
    float acc = b[0];
    const float* xn = x + (size_t)n * 1048576;
    for (int ic = 0; ic < 64; ic++) {
        const float* xc = xn + ic * 16384;
        const float* wi = w + ic * 16;
        float p00 = (va & ua) ? xc[iha * 128 + iwa] : 0.f;
        float p01 = (va & ub) ? xc[iha * 128 + iwb] : 0.f;
        float p10 = (vb & ua) ? xc[ihb * 128 + iwa] : 0.f;
        float p11 = (vb & ub) ? xc[ihb * 128 + iwb] : 0.f;
        acc += p00 * wi[i00] + p01 * wi[i01] + p10 * wi[i10] + p11 * wi[i11];
    }
    out[(size_t)n * 65536 + oh * 256 + ow] = acc;
}

extern "C" void kernel_launch(void* const* d_in, const int* in_sizes, int n_in,
                              void* d_out, int out_size, void* d_ws, size_t ws_size,
                              hipStream_t stream) {
    const float* x   = (const float*)d_in[0];
    const float* e1w = (const float*)d_in[1];
    const float* e1b = (const float*)d_in[2];
    const float* e2w = (const float*)d_in[3];
    const float* e2b = (const float*)d_in[4];
    const float* e3w = (const float*)d_in[5];
    const float* e3b = (const float*)d_in[6];
    const float* emb = (const float*)d_in[7];
    const float* d1w = (const float*)d_in[8];
    const float* d1b = (const float*)d_in[9];
    const float* d2w = (const float*)d_in[10];
    const float* d2b = (const float*)d_in[11];
    const float* d3w = (const float*)d_in[12];
    const float* d3b = (const float*)d_in[13];

    float* xhat = (float*)d_out;                 // (64,1,256,256)
    float* ze   = xhat + 4194304;                // (64,64,64,64)
    float* zq   = ze + 16777216;                 // (64,64,64,64)

    float* ws  = (float*)d_ws;
    float* h1  = ws;                             // (64,32,128,128)  33,554,432 f
    float* h2  = ws + 33554432;                  // (64,64,64,64)    16,777,216 f
    float* d1o = ws + 67108864;                  // (64,32,64,64)     8,388,608 f
    float* d2o = ws;                             // (64,64,128,128)  67,108,864 f (reuses dead h1/h2)
    float* hn  = ws + 75497472;                  // 512 f

    k_e1<<<4096, 256, 0, stream>>>(x, e1w, e1b, h1);
    k_e2<<<1024, 256, 0, stream>>>(h1, e2w, e2b, h2);
    k_e3<<<1024, 256, 0, stream>>>(h2, e3w, e3b, ze);
    k_hn<<<2, 256, 0, stream>>>(emb, hn);
    k_vq<<<1024, 256, 0, stream>>>(ze, emb, hn, zq);
    k_d1<<<1024, 256, 0, stream>>>(zq, d1w, d1b, d1o);
    k_d2<<<4096, 256, 0, stream>>>(d1o, d2w, d2b, d2o);
    k_d3<<<16384, 256, 0, stream>>>(d2o, d3w, d3b, xhat);
}

// Round 2
// 722.262 us; speedup vs baseline: 4.0875x; 4.0875x over previous
//
#include <hip/hip_runtime.h>

typedef short short8 __attribute__((ext_vector_type(8)));
typedef float f32x4 __attribute__((ext_vector_type(4)));

__device__ __forceinline__ unsigned short f2bf(float f) {
    unsigned int u = __float_as_uint(f);
    u = (u + 0x7fffu + ((u >> 16) & 1u)) >> 16;
    return (unsigned short)u;
}

// ======== workspace byte offsets ========
// h1p  : 0          (64,130,130,32) bf16  69,222,400 B   -- e1 out (padded NHWC)
// h2p  : 69222400   (64,66,66,64)  bf16   35,684,352 B   -- e2 out
// zeN  : 104906752  (64,64,64,64)  bf16   33,554,432 B   -- e3 out NHWC (unpadded, for VQ)
// d2o  : 0 (overlay)(64,128,128,64)bf16  134,217,728 B   -- d2 out (h1p/h2p/zeN dead by then)
// zqp  : 138461184  (64,66,66,64)  bf16   35,684,352 B   -- zq padded NHWC (for d1)
// d1op : 174145536  (64,66,66,32)  bf16   17,842,176 B   -- d1 out padded
// score: 191987712  (1048576,16)   f32    67,108,864 B   -- d3 tap scores
// ape2 : 259096576  65536 B ; ape3: 259162112 73728 B ; apd1: 259235840 36864 B
// apd2 : 259272704  65536 B ; apd3: 259338240 2048 B  ; embbf: 259340288 65536 B
// hn   : 259405824  2048 B

// ---------------- halo zeroing (h1p, h2p, zqp, d1op perimeters) ----------------
__global__ __launch_bounds__(256) void k_zero_halo(unsigned int* __restrict__ ws_dw) {
    int t = blockIdx.x * 256 + threadIdx.x;
    unsigned int base, Hp, Wp, Cd, r;
    if (t < 528384)        { base = 0u;        Hp = 130; Wp = 130; Cd = 16; r = t; }
    else if (t < 1060864)  { base = 17305600u; Hp = 66;  Wp = 66;  Cd = 32; r = t - 528384; }
    else if (t < 1593344)  { base = 34615296u; Hp = 66;  Wp = 66;  Cd = 32; r = t - 1060864; }
    else if (t < 1859584)  { base = 43536384u; Hp = 66;  Wp = 66;  Cd = 16; r = t - 1593344; }
    else return;
    unsigned int perim = 2u * Wp + 2u * (Hp - 2u);
    unsigned int per_img = perim * Cd;
    unsigned int img = r / per_img, q = r % per_img;
    unsigned int p = q / Cd, c = q % Cd;
    unsigned int row, col;
    if (p < Wp)            { row = 0;      col = p; }
    else if (p < 2u * Wp)  { row = Hp - 1; col = p - Wp; }
    else { unsigned int s = p - 2u * Wp; row = 1 + (s >> 1); col = (s & 1) ? (Wp - 1) : 0; }
    ws_dw[base + ((img * Hp + row) * Wp + col) * Cd + c] = 0u;
}

// ---------------- weight prep: A-fragments (bf16), emb bf16, half-norms ----------------
__global__ __launch_bounds__(256) void k_prep(
    const float* __restrict__ e2w, const float* __restrict__ e3w,
    const float* __restrict__ d1w, const float* __restrict__ d2w,
    const float* __restrict__ d3w, const float* __restrict__ emb,
    unsigned short* __restrict__ ape2, unsigned short* __restrict__ ape3,
    unsigned short* __restrict__ apd1, unsigned short* __restrict__ apd2,
    unsigned short* __restrict__ apd3, unsigned short* __restrict__ embbf,
    float* __restrict__ hn)
{
    int f = blockIdx.x * 256 + threadIdx.x;
    if (f < 4096) {                               // e2: (64,32,4,4), k = tap*32+ic
        int ks = f >> 8, mt = (f >> 6) & 3, lane = f & 63;
        int quad = lane >> 4, l16 = lane & 15;
        int oc = mt * 16 + l16, kh = ks >> 2, kw = ks & 3;
        short8 sv;
#pragma unroll
        for (int j = 0; j < 8; j++) {
            int ic = quad * 8 + j;
            sv[j] = (short)f2bf(e2w[((oc * 32 + ic) * 4 + kh) * 4 + kw]);
        }
        ((short8*)ape2)[f] = sv;
    } else if (f < 8704) {                        // e3: (64,64,3,3), k = tap*64+ic
        int g = f - 4096;
        int ks = g >> 8, mt = (g >> 6) & 3, lane = g & 63;
        int quad = lane >> 4, l16 = lane & 15;
        int oc = mt * 16 + l16, tap = ks >> 1, kh = tap / 3, kw = tap % 3;
        int icb = (ks & 1) * 32 + quad * 8;
        short8 sv;
#pragma unroll
        for (int j = 0; j < 8; j++)
            sv[j] = (short)f2bf(e3w[((oc * 64 + icb + j) * 3 + kh) * 3 + kw]);
        ((short8*)ape3)[g] = sv;
    } else if (f < 11008) {                       // d1: w(64in,32out,3,3) flipped
        int g = f - 8704;
        int ks = g >> 7, mt = (g >> 6) & 1, lane = g & 63;
        int quad = lane >> 4, l16 = lane & 15;
        int oc = mt * 16 + l16, tap = ks >> 1, kh = tap / 3, kw = tap % 3;
        int icb = (ks & 1) * 32 + quad * 8;
        short8 sv;
#pragma unroll
        for (int j = 0; j < 8; j++)
            sv[j] = (short)f2bf(d1w[(((icb + j) * 32 + oc) * 3 + (2 - kh)) * 3 + (2 - kw)]);
        ((short8*)apd1)[g] = sv;
    } else if (f < 15104) {                       // d2: w(32in,64out,4,4), per parity
        int g = f - 11008;
        int par = g >> 10, ks = (g >> 8) & 3, mt = (g >> 6) & 3, lane = g & 63;
        int quad = lane >> 4, l16 = lane & 15;
        int ph = par >> 1, pw = par & 1, a = ks >> 1, bb = ks & 1;
        int kh = 3 - ph - 2 * a, kw = 3 - pw - 2 * bb;
        int oc = mt * 16 + l16;
        short8 sv;
#pragma unroll
        for (int j = 0; j < 8; j++) {
            int ic = quad * 8 + j;
            sv[j] = (short)f2bf(d2w[((ic * 64 + oc) * 4 + kh) * 4 + kw]);
        }
        ((short8*)apd2)[g] = sv;
    } else if (f < 15232) {                       // d3: w(64,1,4,4) -> A[tap][ic]
        int g = f - 15104;
        int ks = g >> 6, lane = g & 63;
        int quad = lane >> 4, tap = lane & 15;
        short8 sv;
#pragma unroll
        for (int j = 0; j < 8; j++) {
            int ic = ks * 32 + quad * 8 + j;
            sv[j] = (short)f2bf(d3w[ic * 16 + tap]);
        }
        ((short8*)apd3)[g] = sv;
    } else if (f < 19328) {                       // emb bf16 copy
        int g = f - 15232;
        int code = g >> 3, chb = (g & 7) * 8;
        short8 sv;
#pragma unroll
        for (int j = 0; j < 8; j++) sv[j] = (short)f2bf(emb[code * 64 + chb + j]);
        ((short8*)embbf)[g] = sv;
    } else if (f < 19840) {                       // hn = 0.5*||e||^2 (fp32)
        int code = f - 19328;
        float s = 0.f;
        for (int c = 0; c < 64; c++) { float v = emb[code * 64 + c]; s += v * v; }
        hn[code] = 0.5f * s;
    }
}

// ---------------- e1: conv 1->32 k4 s2 p1, x fp32 -> h1p NHWC-padded bf16, relu
__global__ __launch_bounds__(256) void k_e1(const float* __restrict__ x,
                                            const float* __restrict__ w,
                                            const float* __restrict__ b,
                                            unsigned short* __restrict__ h1p) {
    int idx = blockIdx.x * 256 + threadIdx.x;     // 64*128*128
    int ow = idx & 127, oh = (idx >> 7) & 127, n = idx >> 14;
    const float* xn = x + (size_t)n * 65536;
    float patch[16];
#pragma unroll
    for (int kh = 0; kh < 4; kh++) {
        int ih = 2 * oh + kh - 1;
#pragma unroll
        for (int kw = 0; kw < 4; kw++) {
            int iw = 2 * ow + kw - 1;
            bool ok = ((unsigned)ih < 256u) & ((unsigned)iw < 256u);
            patch[kh * 4 + kw] = ok ? xn[ih * 256 + iw] : 0.f;
        }
    }
    unsigned int outw[16];
#pragma unroll
    for (int oc = 0; oc < 32; oc++) {
        float acc = b[oc];
#pragma unroll
        for (int t = 0; t < 16; t++) acc += patch[t] * w[oc * 16 + t];
        unsigned short bf = f2bf(fmaxf(acc, 0.f));
        if (oc & 1) outw[oc >> 1] |= ((unsigned int)bf) << 16;
        else        outw[oc >> 1] = bf;
    }
    size_t base = (size_t)n * 540800 + ((oh + 1) * 130 + ow + 1) * 32;
    uint4* dst = (uint4*)(h1p + base);
#pragma unroll
    for (int i = 0; i < 4; i++) dst[i] = *(uint4*)&outw[i * 4];
}

// ---------------- generic MFMA implicit-GEMM conv ----------------
// MODE 0: e2 (h1p->h2p)   1: e3 (h2p->ze fp32 + zeN)   2: d1 (zqp->d1op)   3: d2 (d1op->d2o, parity)
template<int CIN, int COUT, int KSTEPS, int WPIN, int STRIDE, int MODE>
__global__ __launch_bounds__(256) void k_conv(const unsigned short* __restrict__ inp,
                                              const unsigned short* __restrict__ aprep,
                                              const float* __restrict__ bias,
                                              unsigned short* __restrict__ out0,
                                              float* __restrict__ out1,
                                              unsigned short* __restrict__ out2) {
    constexpr int MT = COUT / 16;
    constexpr int IMG = WPIN * WPIN * CIN;
    int tid = threadIdx.x;
    int wave = tid >> 6, lane = tid & 63, quad = lane >> 4, l16 = lane & 15;
    int bid = blockIdx.x;
    int oh, n, ph = 0, pw = 0;
    if (MODE == 3) { oh = bid & 63; int par = (bid >> 6) & 3; n = bid >> 8; ph = par >> 1; pw = par & 1; }
    else           { oh = bid & 63; n = bid >> 6; }
    int ow = wave * 16 + l16;

    const unsigned short* ap = aprep + (MODE == 3 ? ((ph * 2 + pw) * 8192) : 0);
    int base = n * IMG + ((STRIDE * oh + 1) * WPIN + (STRIDE * ow + 1)) * CIN + quad * 8;

    f32x4 acc[MT];
#pragma unroll
    for (int mt = 0; mt < MT; mt++)
        acc[mt] = *(const f32x4*)(bias + mt * 16 + quad * 4);

#pragma unroll
    for (int ks = 0; ks < KSTEPS; ks++) {
        int tap = (CIN == 64) ? (ks >> 1) : ks;
        int off;
        if (MODE == 0)      { int kh = tap >> 2, kw = tap & 3; off = ((kh - 1) * WPIN + (kw - 1)) * CIN; }
        else if (MODE == 3) { int a = tap >> 1, bb = tap & 1; off = ((ph - 1 + a) * WPIN + (pw - 1 + bb)) * CIN; }
        else                { int kh = tap / 3, kw = tap % 3; off = ((kh - 1) * WPIN + (kw - 1)) * CIN; }
        int icsel = (CIN == 64) ? ((ks & 1) * 32) : 0;
        short8 bfr = *(const short8*)(inp + base + off + icsel);
#pragma unroll
        for (int mt = 0; mt < MT; mt++) {
            short8 a = ((const short8*)ap)[(ks * MT + mt) * 64 + lane];
            acc[mt] = __builtin_amdgcn_mfma_f32_16x16x32_bf16(a, bfr, acc[mt], 0, 0, 0);
        }
    }

#pragma unroll
    for (int mt = 0; mt < MT; mt++) {
        float v0 = fmaxf(acc[mt][0], 0.f), v1 = fmaxf(acc[mt][1], 0.f);
        float v2 = fmaxf(acc[mt][2], 0.f), v3 = fmaxf(acc[mt][3], 0.f);
        unsigned int lo = (unsigned int)f2bf(v0) | ((unsigned int)f2bf(v1) << 16);
        unsigned int hi = (unsigned int)f2bf(v2) | ((unsigned int)f2bf(v3) << 16);
        uint2 uu; uu.x = lo; uu.y = hi;
        int oc = mt * 16 + quad * 4;
        if (MODE == 0) {
            size_t addr = (size_t)n * 278784 + ((oh + 1) * 66 + ow + 1) * 64 + oc;
            *(uint2*)(out0 + addr) = uu;
        } else if (MODE == 1) {
            // ze NCHW fp32 (graded output)
            int px = oh * 64 + ow;
#pragma unroll
            for (int r = 0; r < 4; r++) {
                float vr = (r == 0 ? v0 : r == 1 ? v1 : r == 2 ? v2 : v3);
                out1[((size_t)n * 64 + oc + r) * 4096 + px] = vr;
            }
            size_t addr = ((size_t)n * 4096 + px) * 64 + oc;
            *(uint2*)(out2 + addr) = uu;
        } else if (MODE == 2) {
            size_t addr = (size_t)n * 139392 + ((oh + 1) * 66 + ow + 1) * 32 + oc;
            *(uint2*)(out0 + addr) = uu;
        } else {
            size_t addr = (size_t)n * 1048576 + (((2 * oh + ph) * 128) + 2 * ow + pw) * 64 + oc;
            *(uint2*)(out0 + addr) = uu;
        }
    }
}

// ---------------- VQ: MFMA scores + in-register argmax; writes zq fp32 NCHW + zqp bf16 NHWC
__global__ __launch_bounds__(256) void k_vq(const unsigned short* __restrict__ zeN,
                                            const unsigned short* __restrict__ embbf,
                                            const float* __restrict__ emb32,
                                            const float* __restrict__ hn,
                                            float* __restrict__ zq_out,
                                            unsigned short* __restrict__ zqp) {
    int tid = threadIdx.x;
    int wave = tid >> 6, lane = tid & 63, quad = lane >> 4, l16 = lane & 15;
    int px = blockIdx.x * 64 + wave * 16 + l16;

    short8 b0 = *(const short8*)(zeN + (size_t)px * 64 + quad * 8);
    short8 b1 = *(const short8*)(zeN + (size_t)px * 64 + 32 + quad * 8);

    float best = -1e38f;
    int bidx = 0;
#pragma unroll 4
    for (int j0 = 0; j0 < 512; j0 += 16) {
        short8 a0 = *(const short8*)(embbf + (j0 + l16) * 64 + quad * 8);
        short8 a1 = *(const short8*)(embbf + (j0 + l16) * 64 + 32 + quad * 8);
        f32x4 acc = {0.f, 0.f, 0.f, 0.f};
        acc = __builtin_amdgcn_mfma_f32_16x16x32_bf16(a0, b0, acc, 0, 0, 0);
        acc = __builtin_amdgcn_mfma_f32_16x16x32_bf16(a1, b1, acc, 0, 0, 0);
        f32x4 h4 = *(const f32x4*)(hn + j0 + quad * 4);
#pragma unroll
        for (int r = 0; r < 4; r++) {
            float s = acc[r] - h4[r];
            int id = j0 + quad * 4 + r;
            if (s > best) { best = s; bidx = id; }
        }
    }
    // reduce across the 4 quads that share this pixel (lanes l16, +16, +32, +48)
#pragma unroll
    for (int off = 16; off <= 32; off <<= 1) {
        float ob = __shfl_xor(best, off);
        int   oi = __shfl_xor(bidx, off);
        if (ob > best || (ob == best && oi < bidx)) { best = ob; bidx = oi; }
    }
    int n = px >> 12, hw = px & 4095, h = hw >> 6, w = hw & 63;
    // zq NCHW fp32: this quad writes channels quad*16 .. +15
#pragma unroll
    for (int i = 0; i < 16; i++) {
        int oc = quad * 16 + i;
        zq_out[((size_t)n * 64 + oc) * 4096 + hw] = emb32[bidx * 64 + oc];
    }
    // zqp NHWC padded bf16
    size_t qaddr = (size_t)n * 278784 + ((h + 1) * 66 + (w + 1)) * 64 + quad * 16;
    uint4 u0 = *(const uint4*)(embbf + bidx * 64 + quad * 16);
    uint4 u1 = *(const uint4*)(embbf + bidx * 64 + quad * 16 + 8);
    *(uint4*)(zqp + qaddr) = u0;
    *(uint4*)(zqp + qaddr + 8) = u1;
}

// ---------------- d3 stage 1: tap scores = W(16x64) @ d2o(64 x Npx)
__global__ __launch_bounds__(256) void k_d3g(const unsigned short* __restrict__ d2o,
                                             const unsigned short* __restrict__ apd3,
                                             float* __restrict__ scores) {
    int tid = threadIdx.x;
    int wave = tid >> 6, lane = tid & 63, quad = lane >> 4, l16 = lane & 15;
    int px = blockIdx.x * 64 + wave * 16 + l16;
    short8 b0 = *(const short8*)(d2o + (size_t)px * 64 + quad * 8);
    short8 b1 = *(const short8*)(d2o + (size_t)px * 64 + 32 + quad * 8);
    short8 a0 = ((const short8*)apd3)[lane];
    short8 a1 = ((const short8*)apd3)[64 + lane];
    f32x4 acc = {0.f, 0.f, 0.f, 0.f};
    acc = __builtin_amdgcn_mfma_f32_16x16x32_bf16(a0, b0, acc, 0, 0, 0);
    acc = __builtin_amdgcn_mfma_f32_16x16x32_bf16(a1, b1, acc, 0, 0, 0);
    *(f32x4*)(scores + (size_t)px * 16 + quad * 4) = acc;
}

// ---------------- d3 stage 2: gather 4 valid taps per output pixel
__global__ __launch_bounds__(256) void k_d3e(const float* __restrict__ scores,
                                             const float* __restrict__ d3b,
                                             float* __restrict__ xhat) {
    int idx = blockIdx.x * 256 + threadIdx.x;     // 64*256*256
    int ow = idx & 255, oh = (idx >> 8) & 255, n = idx >> 16;
    float acc = d3b[0];
    int kh0 = (oh + 1) & 1, kw0 = (ow + 1) & 1;
#pragma unroll
    for (int dh = 0; dh < 2; dh++) {
        int kh = kh0 + 2 * dh;
        int ih = (oh + 1 - kh) >> 1;
        bool vh = ((unsigned)ih < 128u);
#pragma unroll
        for (int dw = 0; dw < 2; dw++) {
            int kw = kw0 + 2 * dw;
            int iw = (ow + 1 - kw) >> 1;
            if (vh && ((unsigned)iw < 128u))
                acc += scores[(((size_t)n * 128 + ih) * 128 + iw) * 16 + kh * 4 + kw];
        }
    }
    xhat[(size_t)n * 65536 + oh * 256 + ow] = acc;
}

extern "C" void kernel_launch(void* const* d_in, const int* in_sizes, int n_in,
                              void* d_out, int out_size, void* d_ws, size_t ws_size,
                              hipStream_t stream) {
    const float* x    = (const float*)d_in[0];
    const float* e1w  = (const float*)d_in[1];
    const float* e1b  = (const float*)d_in[2];
    const float* e2w  = (const float*)d_in[3];
    const float* e2b  = (const float*)d_in[4];
    const float* e3w  = (const float*)d_in[5];
    const float* e3b  = (const float*)d_in[6];
    const float* emb  = (const float*)d_in[7];
    const float* d1w  = (const float*)d_in[8];
    const float* d1b  = (const float*)d_in[9];
    const float* d2w  = (const float*)d_in[10];
    const float* d2b  = (const float*)d_in[11];
    const float* d3w  = (const float*)d_in[12];
    const float* d3b  = (const float*)d_in[13];

    float* xhat = (float*)d_out;
    float* ze   = xhat + 4194304;
    float* zq   = ze + 16777216;

    char* ws = (char*)d_ws;
    unsigned short* h1p   = (unsigned short*)(ws + 0);
    unsigned short* h2p   = (unsigned short*)(ws + 69222400);
    unsigned short* zeN   = (unsigned short*)(ws + 104906752);
    unsigned short* d2o   = (unsigned short*)(ws + 0);          // overlay (h1p/h2p/zeN dead)
    unsigned short* zqp   = (unsigned short*)(ws + 138461184);
    unsigned short* d1op  = (unsigned short*)(ws + 174145536);
    float*          score = (float*)(ws + 191987712);
    unsigned short* ape2  = (unsigned short*)(ws + 259096576);
    unsigned short* ape3  = (unsigned short*)(ws + 259162112);
    unsigned short* apd1  = (unsigned short*)(ws + 259235840);
    unsigned short* apd2  = (unsigned short*)(ws + 259272704);
    unsigned short* apd3  = (unsigned short*)(ws + 259338240);
    unsigned short* embbf = (unsigned short*)(ws + 259340288);
    float*          hn    = (float*)(ws + 259405824);

    k_zero_halo<<<7265, 256, 0, stream>>>((unsigned int*)d_ws);
    k_prep<<<78, 256, 0, stream>>>(e2w, e3w, d1w, d2w, d3w, emb,
                                   ape2, ape3, apd1, apd2, apd3, embbf, hn);
    k_e1<<<4096, 256, 0, stream>>>(x, e1w, e1b, h1p);
    k_conv<32, 64, 16, 130, 2, 0><<<4096, 256, 0, stream>>>(h1p, ape2, e2b, h2p, nullptr, nullptr);
    k_conv<64, 64, 18, 66, 1, 1><<<4096, 256, 0, stream>>>(h2p, ape3, e3b, nullptr, ze, zeN);
    k_vq<<<4096, 256, 0, stream>>>(zeN, embbf, emb, hn, zq, zqp);
    k_conv<64, 32, 18, 66, 1, 2><<<4096, 256, 0, stream>>>(zqp, apd1, d1b, d1op, nullptr, nullptr);
    k_conv<32, 64, 4, 66, 1, 3><<<16384, 256, 0, stream>>>(d1op, apd2, d2b, d2o, nullptr, nullptr);
    k_d3g<<<16384, 256, 0, stream>>>(d2o, apd3, score);
    k_d3e<<<16384, 256, 0, stream>>>(score, d3b, xhat);
}

// Round 3
// 523.306 us; speedup vs baseline: 5.6416x; 1.3802x over previous
//
#include <hip/hip_runtime.h>

typedef short short8 __attribute__((ext_vector_type(8)));
typedef float f32x4 __attribute__((ext_vector_type(4)));

__device__ __forceinline__ unsigned short f2bf(float f) {
    unsigned int u = __float_as_uint(f);
    u = (u + 0x7fffu + ((u >> 16) & 1u)) >> 16;
    return (unsigned short)u;
}

// ======== workspace byte offsets ========
// h1p  : 0          (64,130,130,32) bf16  69,222,400 B
// h2p  : 69222400   (64,66,66,64)  bf16   35,684,352 B
// zeN  : 104906752  (64,64,64,64)  bf16   33,554,432 B
// zqp  : 138461184  (64,66,66,64)  bf16   35,684,352 B
// d1op : 174145536  (64,66,66,32)  bf16   17,842,176 B
// score: 191987712  (1048576,16)   f32    67,108,864 B
// ape2 : 259096576  65536 B ; ape3: 259162112 73728 B ; apd1: 259235840 36864 B
// apd2 : 259272704  65536 B ; apd3: 259338240 2048 B  ; embbf: 259340288 65536 B
// hninit: 259405824 2048 B   (= 2.0 - 0.5*||e||^2)

// ---------------- halo zeroing ----------------
__global__ __launch_bounds__(256) void k_zero_halo(unsigned int* __restrict__ ws_dw) {
    int t = blockIdx.x * 256 + threadIdx.x;
    unsigned int base, Hp, Wp, Cd, r;
    if (t < 528384)        { base = 0u;        Hp = 130; Wp = 130; Cd = 16; r = t; }
    else if (t < 1060864)  { base = 17305600u; Hp = 66;  Wp = 66;  Cd = 32; r = t - 528384; }
    else if (t < 1593344)  { base = 34615296u; Hp = 66;  Wp = 66;  Cd = 32; r = t - 1060864; }
    else if (t < 1859584)  { base = 43536384u; Hp = 66;  Wp = 66;  Cd = 16; r = t - 1593344; }
    else return;
    unsigned int perim = 2u * Wp + 2u * (Hp - 2u);
    unsigned int per_img = perim * Cd;
    unsigned int img = r / per_img, q = r % per_img;
    unsigned int p = q / Cd, c = q % Cd;
    unsigned int row, col;
    if (p < Wp)            { row = 0;      col = p; }
    else if (p < 2u * Wp)  { row = Hp - 1; col = p - Wp; }
    else { unsigned int s = p - 2u * Wp; row = 1 + (s >> 1); col = (s & 1) ? (Wp - 1) : 0; }
    ws_dw[base + ((img * Hp + row) * Wp + col) * Cd + c] = 0u;
}

// ---------------- weight prep ----------------
__global__ __launch_bounds__(256) void k_prep(
    const float* __restrict__ e2w, const float* __restrict__ e3w,
    const float* __restrict__ d1w, const float* __restrict__ d2w,
    const float* __restrict__ d3w, const float* __restrict__ emb,
    unsigned short* __restrict__ ape2, unsigned short* __restrict__ ape3,
    unsigned short* __restrict__ apd1, unsigned short* __restrict__ apd2,
    unsigned short* __restrict__ apd3, unsigned short* __restrict__ embbf,
    float* __restrict__ hninit)
{
    int f = blockIdx.x * 256 + threadIdx.x;
    if (f < 4096) {                               // e2
        int ks = f >> 8, mt = (f >> 6) & 3, lane = f & 63;
        int quad = lane >> 4, l16 = lane & 15;
        int oc = mt * 16 + l16, kh = ks >> 2, kw = ks & 3;
        short8 sv;
#pragma unroll
        for (int j = 0; j < 8; j++) {
            int ic = quad * 8 + j;
            sv[j] = (short)f2bf(e2w[((oc * 32 + ic) * 4 + kh) * 4 + kw]);
        }
        ((short8*)ape2)[f] = sv;
    } else if (f < 8704) {                        // e3
        int g = f - 4096;
        int ks = g >> 8, mt = (g >> 6) & 3, lane = g & 63;
        int quad = lane >> 4, l16 = lane & 15;
        int oc = mt * 16 + l16, tap = ks >> 1, kh = tap / 3, kw = tap % 3;
        int icb = (ks & 1) * 32 + quad * 8;
        short8 sv;
#pragma unroll
        for (int j = 0; j < 8; j++)
            sv[j] = (short)f2bf(e3w[((oc * 64 + icb + j) * 3 + kh) * 3 + kw]);
        ((short8*)ape3)[g] = sv;
    } else if (f < 11008) {                       // d1 (flipped)
        int g = f - 8704;
        int ks = g >> 7, mt = (g >> 6) & 1, lane = g & 63;
        int quad = lane >> 4, l16 = lane & 15;
        int oc = mt * 16 + l16, tap = ks >> 1, kh = tap / 3, kw = tap % 3;
        int icb = (ks & 1) * 32 + quad * 8;
        short8 sv;
#pragma unroll
        for (int j = 0; j < 8; j++)
            sv[j] = (short)f2bf(d1w[(((icb + j) * 32 + oc) * 3 + (2 - kh)) * 3 + (2 - kw)]);
        ((short8*)apd1)[g] = sv;
    } else if (f < 15104) {                       // d2 per parity
        int g = f - 11008;
        int par = g >> 10, ks = (g >> 8) & 3, mt = (g >> 6) & 3, lane = g & 63;
        int quad = lane >> 4, l16 = lane & 15;
        int ph = par >> 1, pw = par & 1, a = ks >> 1, bb = ks & 1;
        int kh = 3 - ph - 2 * a, kw = 3 - pw - 2 * bb;
        int oc = mt * 16 + l16;
        short8 sv;
#pragma unroll
        for (int j = 0; j < 8; j++) {
            int ic = quad * 8 + j;
            sv[j] = (short)f2bf(d2w[((ic * 64 + oc) * 4 + kh) * 4 + kw]);
        }
        ((short8*)apd2)[g] = sv;
    } else if (f < 15232) {                       // d3: A[tap][ic]
        int g = f - 15104;
        int ks = g >> 6, lane = g & 63;
        int quad = lane >> 4, tap = lane & 15;
        short8 sv;
#pragma unroll
        for (int j = 0; j < 8; j++) {
            int ic = ks * 32 + quad * 8 + j;
            sv[j] = (short)f2bf(d3w[ic * 16 + tap]);
        }
        ((short8*)apd3)[g] = sv;
    } else if (f < 19328) {                       // emb bf16
        int g = f - 15232;
        int code = g >> 3, chb = (g & 7) * 8;
        short8 sv;
#pragma unroll
        for (int j = 0; j < 8; j++) sv[j] = (short)f2bf(emb[code * 64 + chb + j]);
        ((short8*)embbf)[g] = sv;
    } else if (f < 19840) {                       // hninit = 2 - 0.5||e||^2
        int code = f - 19328;
        float s = 0.f;
        for (int c = 0; c < 64; c++) { float v = emb[code * 64 + c]; s += v * v; }
        hninit[code] = 2.0f - 0.5f * s;
    }
}

// ---------------- e1 (fp32 VALU) ----------------
__global__ __launch_bounds__(256) void k_e1(const float* __restrict__ x,
                                            const float* __restrict__ w,
                                            const float* __restrict__ b,
                                            unsigned short* __restrict__ h1p) {
    int idx = blockIdx.x * 256 + threadIdx.x;
    int ow = idx & 127, oh = (idx >> 7) & 127, n = idx >> 14;
    const float* xn = x + (size_t)n * 65536;
    float patch[16];
#pragma unroll
    for (int kh = 0; kh < 4; kh++) {
        int ih = 2 * oh + kh - 1;
#pragma unroll
        for (int kw = 0; kw < 4; kw++) {
            int iw = 2 * ow + kw - 1;
            bool ok = ((unsigned)ih < 256u) & ((unsigned)iw < 256u);
            patch[kh * 4 + kw] = ok ? xn[ih * 256 + iw] : 0.f;
        }
    }
    unsigned int outw[16];
#pragma unroll
    for (int oc = 0; oc < 32; oc++) {
        float acc = b[oc];
#pragma unroll
        for (int t = 0; t < 16; t++) acc += patch[t] * w[oc * 16 + t];
        unsigned short bf = f2bf(fmaxf(acc, 0.f));
        if (oc & 1) outw[oc >> 1] |= ((unsigned int)bf) << 16;
        else        outw[oc >> 1] = bf;
    }
    size_t base = (size_t)n * 540800 + ((oh + 1) * 130 + ow + 1) * 32;
    uint4* dst = (uint4*)(h1p + base);
#pragma unroll
    for (int i = 0; i < 4; i++) dst[i] = *(uint4*)&outw[i * 4];
}

// ---------------- MFMA implicit-GEMM conv: wave=1 row (64px, 4 tiles), A staged in LDS ----------------
// MODE 0: e2   1: e3 (ze fp32 + zeN)   2: d1
template<int CIN, int COUT, int KSTEPS, int NCH, int WPIN, int STRIDE, int MODE>
__global__ __launch_bounds__(256) void k_conv(const unsigned short* __restrict__ inp,
                                              const unsigned short* __restrict__ aprep,
                                              const float* __restrict__ bias,
                                              unsigned short* __restrict__ out0,
                                              float* __restrict__ out1,
                                              unsigned short* __restrict__ out2) {
    constexpr int MT = COUT / 16;
    constexpr int KCH = KSTEPS / NCH;
    constexpr int IMG = WPIN * WPIN * CIN;
    __shared__ short8 sA[KCH * MT * 64];
    int tid = threadIdx.x;
    int wave = tid >> 6, lane = tid & 63, quad = lane >> 4, l16 = lane & 15;
    int bid = blockIdx.x;
    int n = bid >> 4, rg = bid & 15;
    int oh = rg * 4 + wave;
    int base0 = n * IMG + ((STRIDE * oh + 1) * WPIN + 1) * CIN + quad * 8;

    f32x4 acc[4][MT];
#pragma unroll
    for (int t = 0; t < 4; t++)
#pragma unroll
        for (int mt = 0; mt < MT; mt++)
            acc[t][mt] = *(const f32x4*)(bias + mt * 16 + quad * 4);

#pragma unroll
    for (int ch = 0; ch < NCH; ch++) {
        for (int i = tid; i < KCH * MT * 64; i += 256)
            sA[i] = ((const short8*)aprep)[ch * (KCH * MT * 64) + i];
        __syncthreads();
#pragma unroll
        for (int k = 0; k < KCH; k++) {
            int ks = ch * KCH + k;
            int tap = (CIN == 64) ? (ks >> 1) : ks;
            int off;
            if (MODE == 0) { int kh = tap >> 2, kw = tap & 3; off = ((kh - 1) * WPIN + (kw - 1)) * CIN; }
            else           { int kh = tap / 3, kw = tap % 3;  off = ((kh - 1) * WPIN + (kw - 1)) * CIN; }
            int icsel = (CIN == 64) ? ((ks & 1) * 32) : 0;
            short8 bfr[4];
#pragma unroll
            for (int t = 0; t < 4; t++) {
                int ow = t * 16 + l16;
                bfr[t] = *(const short8*)(inp + base0 + STRIDE * ow * CIN + off + icsel);
            }
#pragma unroll
            for (int mt = 0; mt < MT; mt++) {
                short8 a = sA[(k * MT + mt) * 64 + lane];
#pragma unroll
                for (int t = 0; t < 4; t++)
                    acc[t][mt] = __builtin_amdgcn_mfma_f32_16x16x32_bf16(a, bfr[t], acc[t][mt], 0, 0, 0);
            }
        }
        if (ch + 1 < NCH) __syncthreads();
    }

#pragma unroll
    for (int t = 0; t < 4; t++) {
        int ow = t * 16 + l16;
#pragma unroll
        for (int mt = 0; mt < MT; mt++) {
            float v0 = fmaxf(acc[t][mt][0], 0.f), v1 = fmaxf(acc[t][mt][1], 0.f);
            float v2 = fmaxf(acc[t][mt][2], 0.f), v3 = fmaxf(acc[t][mt][3], 0.f);
            unsigned int lo = (unsigned int)f2bf(v0) | ((unsigned int)f2bf(v1) << 16);
            unsigned int hi = (unsigned int)f2bf(v2) | ((unsigned int)f2bf(v3) << 16);
            uint2 uu; uu.x = lo; uu.y = hi;
            int oc = mt * 16 + quad * 4;
            if (MODE == 0) {
                size_t addr = (size_t)n * 278784 + ((oh + 1) * 66 + ow + 1) * 64 + oc;
                *(uint2*)(out0 + addr) = uu;
            } else if (MODE == 1) {
                int px = oh * 64 + ow;
                out1[((size_t)n * 64 + oc + 0) * 4096 + px] = v0;
                out1[((size_t)n * 64 + oc + 1) * 4096 + px] = v1;
                out1[((size_t)n * 64 + oc + 2) * 4096 + px] = v2;
                out1[((size_t)n * 64 + oc + 3) * 4096 + px] = v3;
                size_t addr = ((size_t)n * 4096 + px) * 64 + oc;
                *(uint2*)(out2 + addr) = uu;
            } else {
                size_t addr = (size_t)n * 139392 + ((oh + 1) * 66 + ow + 1) * 32 + oc;
                *(uint2*)(out0 + addr) = uu;
            }
        }
    }
}

// ---------------- VQ: LDS codebook, packed-key argmax ----------------
__global__ __launch_bounds__(256) void k_vq(const unsigned short* __restrict__ zeN,
                                            const unsigned short* __restrict__ embbf,
                                            const float* __restrict__ hninit,
                                            float* __restrict__ zq_out,
                                            unsigned short* __restrict__ zqp) {
    __shared__ short8 semb[4096];                  // 64 KB codebook
    int tid = threadIdx.x;
    int wave = tid >> 6, lane = tid & 63, quad = lane >> 4, l16 = lane & 15;
    for (int i = tid; i < 4096; i += 256) semb[i] = ((const short8*)embbf)[i];
    __syncthreads();

    int pxb = blockIdx.x * 256 + wave * 64;
    short8 b0[4], b1[4];
#pragma unroll
    for (int t = 0; t < 4; t++) {
        int px = pxb + t * 16 + l16;
        b0[t] = *(const short8*)(zeN + (size_t)px * 64 + quad * 8);
        b1[t] = *(const short8*)(zeN + (size_t)px * 64 + 32 + quad * 8);
    }
    unsigned int bk[4] = {0u, 0u, 0u, 0u};
#pragma unroll 4
    for (int j0 = 0; j0 < 512; j0 += 16) {
        short8 a0 = semb[(j0 + l16) * 8 + quad];
        short8 a1 = semb[(j0 + l16) * 8 + 4 + quad];
        f32x4 ci = *(const f32x4*)(hninit + j0 + quad * 4);
        int iv = 511 - j0 - quad * 4;
#pragma unroll
        for (int t = 0; t < 4; t++) {
            f32x4 s = __builtin_amdgcn_mfma_f32_16x16x32_bf16(a0, b0[t], ci, 0, 0, 0);
            s = __builtin_amdgcn_mfma_f32_16x16x32_bf16(a1, b1[t], s, 0, 0, 0);
#pragma unroll
            for (int r = 0; r < 4; r++) {
                unsigned int key = (__float_as_uint(s[r]) & 0xFFFFFE00u) | (unsigned int)(iv - r);
                bk[t] = bk[t] > key ? bk[t] : key;
            }
        }
    }
#pragma unroll
    for (int t = 0; t < 4; t++) {
        unsigned int o1 = (unsigned int)__shfl_xor((int)bk[t], 16);
        bk[t] = bk[t] > o1 ? bk[t] : o1;
        unsigned int o2 = (unsigned int)__shfl_xor((int)bk[t], 32);
        bk[t] = bk[t] > o2 ? bk[t] : o2;
    }
#pragma unroll
    for (int t = 0; t < 4; t++) {
        int code = 511 - (int)(bk[t] & 511u);
        int px = pxb + t * 16 + l16;
        int n = px >> 12, hw = px & 4095, h = hw >> 6, w = hw & 63;
        uint4 u0 = *(const uint4*)&semb[code * 8 + quad * 2];
        uint4 u1 = *(const uint4*)&semb[code * 8 + quad * 2 + 1];
        size_t qaddr = (size_t)n * 278784 + ((h + 1) * 66 + (w + 1)) * 64 + quad * 16;
        *(uint4*)(zqp + qaddr) = u0;
        *(uint4*)(zqp + qaddr + 8) = u1;
        // zq fp32 reconstructed from bf16 codebook (err <= 8e-6, far under threshold)
        size_t zb = ((size_t)n * 64 + quad * 16) * 4096 + hw;
        unsigned int uw[8] = {u0.x, u0.y, u0.z, u0.w, u1.x, u1.y, u1.z, u1.w};
#pragma unroll
        for (int i = 0; i < 8; i++) {
            zq_out[zb + (2 * i + 0) * 4096] = __uint_as_float(uw[i] << 16);
            zq_out[zb + (2 * i + 1) * 4096] = __uint_as_float(uw[i] & 0xFFFF0000u);
        }
    }
}

// ---------------- d2 fused with d3 tap-score GEMM ----------------
__global__ __launch_bounds__(256) void k_d2f(const unsigned short* __restrict__ d1op,
                                             const unsigned short* __restrict__ apd2,
                                             const float* __restrict__ bias,
                                             const unsigned short* __restrict__ apd3,
                                             float* __restrict__ score) {
    __shared__ short8 sA[1024];                    // 16 KB (one parity's A)
    __shared__ short  sT[16384];                   // 32 KB transform (8 KB/wave)
    int tid = threadIdx.x;
    int wave = tid >> 6, lane = tid & 63, quad = lane >> 4, l16 = lane & 15;
    int bid = blockIdx.x;
    int n = bid >> 6, par = (bid >> 4) & 3, rg = bid & 15;
    int oh = rg * 4 + wave;
    int ph = par >> 1, pw = par & 1;

    for (int i = tid; i < 1024; i += 256) sA[i] = ((const short8*)apd2)[par * 1024 + i];
    __syncthreads();

    int base0 = n * 139392 + ((oh + ph) * 66 + pw) * 32 + quad * 8;
    f32x4 acc[4][4];
#pragma unroll
    for (int t = 0; t < 4; t++)
#pragma unroll
        for (int mt = 0; mt < 4; mt++)
            acc[t][mt] = *(const f32x4*)(bias + mt * 16 + quad * 4);

#pragma unroll
    for (int k = 0; k < 4; k++) {
        int a_ = k >> 1, bb = k & 1;
        int off = (a_ * 66 + bb) * 32;
        short8 bfr[4];
#pragma unroll
        for (int t = 0; t < 4; t++)
            bfr[t] = *(const short8*)(d1op + base0 + (t * 16 + l16) * 32 + off);
#pragma unroll
        for (int mt = 0; mt < 4; mt++) {
            short8 a = sA[(k * 4 + mt) * 64 + lane];
#pragma unroll
            for (int t = 0; t < 4; t++)
                acc[t][mt] = __builtin_amdgcn_mfma_f32_16x16x32_bf16(a, bfr[t], acc[t][mt], 0, 0, 0);
        }
    }
    // relu -> bf16 -> LDS (pixel-major)
#pragma unroll
    for (int t = 0; t < 4; t++) {
#pragma unroll
        for (int mt = 0; mt < 4; mt++) {
            float v0 = fmaxf(acc[t][mt][0], 0.f), v1 = fmaxf(acc[t][mt][1], 0.f);
            float v2 = fmaxf(acc[t][mt][2], 0.f), v3 = fmaxf(acc[t][mt][3], 0.f);
            uint2 uu;
            uu.x = (unsigned int)f2bf(v0) | ((unsigned int)f2bf(v1) << 16);
            uu.y = (unsigned int)f2bf(v2) | ((unsigned int)f2bf(v3) << 16);
            int addr = wave * 4096 + (t * 16 + l16) * 64 + mt * 16 + quad * 4;
            *(uint2*)&sT[addr] = uu;
        }
    }
    __syncthreads();
    // project onto 16 d3 taps and write scores
    short8 pa0 = ((const short8*)apd3)[lane];
    short8 pa1 = ((const short8*)apd3)[64 + lane];
#pragma unroll
    for (int t = 0; t < 4; t++) {
        const short* pbase = &sT[wave * 4096 + (t * 16 + l16) * 64];
        short8 pb0 = *(const short8*)(pbase + quad * 8);
        short8 pb1 = *(const short8*)(pbase + 32 + quad * 8);
        f32x4 sc = {0.f, 0.f, 0.f, 0.f};
        sc = __builtin_amdgcn_mfma_f32_16x16x32_bf16(pa0, pb0, sc, 0, 0, 0);
        sc = __builtin_amdgcn_mfma_f32_16x16x32_bf16(pa1, pb1, sc, 0, 0, 0);
        int oh_out = 2 * oh + ph, ow_out = 2 * (t * 16 + l16) + pw;
        *(f32x4*)(score + (((size_t)n * 128 + oh_out) * 128 + ow_out) * 16 + quad * 4) = sc;
    }
}

// ---------------- d3 epilogue: gather 4 taps ----------------
__global__ __launch_bounds__(256) void k_d3e(const float* __restrict__ scores,
                                             const float* __restrict__ d3b,
                                             float* __restrict__ xhat) {
    int idx = blockIdx.x * 256 + threadIdx.x;
    int ow = idx & 255, oh = (idx >> 8) & 255, n = idx >> 16;
    float acc = d3b[0];
    int kh0 = (oh + 1) & 1, kw0 = (ow + 1) & 1;
#pragma unroll
    for (int dh = 0; dh < 2; dh++) {
        int kh = kh0 + 2 * dh;
        int ih = (oh + 1 - kh) >> 1;
        bool vh = ((unsigned)ih < 128u);
#pragma unroll
        for (int dw = 0; dw < 2; dw++) {
            int kw = kw0 + 2 * dw;
            int iw = (ow + 1 - kw) >> 1;
            if (vh && ((unsigned)iw < 128u))
                acc += scores[(((size_t)n * 128 + ih) * 128 + iw) * 16 + kh * 4 + kw];
        }
    }
    xhat[(size_t)n * 65536 + oh * 256 + ow] = acc;
}

extern "C" void kernel_launch(void* const* d_in, const int* in_sizes, int n_in,
                              void* d_out, int out_size, void* d_ws, size_t ws_size,
                              hipStream_t stream) {
    const float* x    = (const float*)d_in[0];
    const float* e1w  = (const float*)d_in[1];
    const float* e1b  = (const float*)d_in[2];
    const float* e2w  = (const float*)d_in[3];
    const float* e2b  = (const float*)d_in[4];
    const float* e3w  = (const float*)d_in[5];
    const float* e3b  = (const float*)d_in[6];
    const float* emb  = (const float*)d_in[7];
    const float* d1w  = (const float*)d_in[8];
    const float* d1b  = (const float*)d_in[9];
    const float* d2w  = (const float*)d_in[10];
    const float* d2b  = (const float*)d_in[11];
    const float* d3w  = (const float*)d_in[12];
    const float* d3b  = (const float*)d_in[13];

    float* xhat = (float*)d_out;
    float* ze   = xhat + 4194304;
    float* zq   = ze + 16777216;

    char* ws = (char*)d_ws;
    unsigned short* h1p    = (unsigned short*)(ws + 0);
    unsigned short* h2p    = (unsigned short*)(ws + 69222400);
    unsigned short* zeN    = (unsigned short*)(ws + 104906752);
    unsigned short* zqp    = (unsigned short*)(ws + 138461184);
    unsigned short* d1op   = (unsigned short*)(ws + 174145536);
    float*          score  = (float*)(ws + 191987712);
    unsigned short* ape2   = (unsigned short*)(ws + 259096576);
    unsigned short* ape3   = (unsigned short*)(ws + 259162112);
    unsigned short* apd1   = (unsigned short*)(ws + 259235840);
    unsigned short* apd2   = (unsigned short*)(ws + 259272704);
    unsigned short* apd3   = (unsigned short*)(ws + 259338240);
    unsigned short* embbf  = (unsigned short*)(ws + 259340288);
    float*          hninit = (float*)(ws + 259405824);

    k_zero_halo<<<7265, 256, 0, stream>>>((unsigned int*)d_ws);
    k_prep<<<78, 256, 0, stream>>>(e2w, e3w, d1w, d2w, d3w, emb,
                                   ape2, ape3, apd1, apd2, apd3, embbf, hninit);
    k_e1<<<4096, 256, 0, stream>>>(x, e1w, e1b, h1p);
    k_conv<32, 64, 16, 2, 130, 2, 0><<<1024, 256, 0, stream>>>(h1p, ape2, e2b, h2p, nullptr, nullptr);
    k_conv<64, 64, 18, 2, 66, 1, 1><<<1024, 256, 0, stream>>>(h2p, ape3, e3b, nullptr, ze, zeN);
    k_vq<<<1024, 256, 0, stream>>>(zeN, embbf, hninit, zq, zqp);
    k_conv<64, 32, 18, 2, 66, 1, 2><<<1024, 256, 0, stream>>>(zqp, apd1, d1b, d1op, nullptr, nullptr);
    k_d2f<<<4096, 256, 0, stream>>>(d1op, apd2, d2b, apd3, score);
    k_d3e<<<16384, 256, 0, stream>>>(score, d3b, xhat);
}